// Round 12
// baseline (707.534 us; speedup 1.0000x reference)
//
#include <hip/hip_runtime.h>
#include <stdint.h>

#define BI 128
#define BT 128
#define KIMG 36
#define LCAP 64
#define DD 1024
#define MP 48        // imgs K padded to 3x16 for MFMA alignment
#define MB 96        // rows per block = 2 padded images
#define NB 256       // cols per block = 4 captions
#define ABUF 6144    // one A staging buffer: 96 rows x 64 B

typedef _Float16 h4 __attribute__((ext_vector_type(4)));
typedef _Float16 h8 __attribute__((ext_vector_type(8)));
typedef float f4 __attribute__((ext_vector_type(4)));

__device__ __forceinline__ float wave_red_sum(float v) {
#pragma unroll
  for (int o = 1; o < 64; o <<= 1) v += __shfl_xor(v, o, 64);
  return v;
}
__device__ __forceinline__ float wave_red_max(float v) {
#pragma unroll
  for (int o = 1; o < 64; o <<= 1) v = fmaxf(v, __shfl_xor(v, o, 64));
  return v;
}

// ---------------------------------------------------------------------------
// Kernel 1: add EPS, L2-normalize rows over D=1024, cast to fp16.
// imgs -> padded row-major [BI*MP][DD] (rows 36..47 of each image = 0).
// caps -> FRAGMENT-MAJOR Bh: tile (r/16, k/32) of 512 halves; within a tile
// half-offset = lane*8 where lane = (kk>>3)*16 + (r&15), kk = k&31. This makes
// a GEMM wave's bf[ni] fragment load one contiguous, coalesced 1 KB segment.
// ---------------------------------------------------------------------------
__global__ __launch_bounds__(256) void norm_kernel(
    const float* __restrict__ imgs, const float* __restrict__ caps,
    _Float16* __restrict__ Ah, _Float16* __restrict__ Bh) {
  int row = blockIdx.x;
  int tid = threadIdx.x;
  const float* src;
  bool isCap;
  int r = 0;
  if (row < BI * MP) {
    int i = row / MP, k = row - i * MP;
    isCap = false;
    if (k >= KIMG) {           // zero padding rows (block-uniform branch)
      h4 z = {};
      ((h4*)(Ah + (size_t)row * DD))[tid] = z;
      return;
    }
    src = imgs + ((size_t)i * KIMG + k) * DD;
  } else {
    r = row - BI * MP;
    isCap = true;
    src = caps + (size_t)r * DD;
  }
  float4 x = ((const float4*)src)[tid];
  x.x += 1e-6f; x.y += 1e-6f; x.z += 1e-6f; x.w += 1e-6f;
  float ss = x.x * x.x + x.y * x.y + x.z * x.z + x.w * x.w;
  ss = wave_red_sum(ss);
  __shared__ float red[4];
  int lane = tid & 63, w = tid >> 6;
  if (lane == 0) red[w] = ss;
  __syncthreads();
  float scale = rsqrtf(red[0] + red[1] + red[2] + red[3]);
  h4 o;
  o[0] = (_Float16)(x.x * scale);
  o[1] = (_Float16)(x.y * scale);
  o[2] = (_Float16)(x.z * scale);
  o[3] = (_Float16)(x.w * scale);
  if (!isCap) {
    ((h4*)(Ah + (size_t)row * DD))[tid] = o;
  } else {
    int k = 4 * tid;
    size_t tile = (size_t)(r >> 4) * 32 + (k >> 5);
    int sub = ((k >> 3) & 3) * 128 + (r & 15) * 8 + (k & 7);
    *(h4*)(Bh + tile * 512 + sub) = o;
  }
}

// ---------------------------------------------------------------------------
// Kernel 2: 2 images x 4 captions per block (96x256), wave w = caption w.
// R11 structure (B never touches LDS):
//  - A (shared by 4 waves): swizzled LDS dbuf, 6 KB/step (12.3 KB total).
//  - B (wave-private): fragment-major coalesced 1KB global->VGPR loads,
//    ping-pong prefetched one step ahead, drained by end-of-step barrier.
// NEW (single lever): __launch_bounds__(256,4) -> 4 blocks/CU (VGPR fits
// 128-cap: acc 96 + frags ~30; LDS 4 x 12.3 KB = 49 KB). TLP is the lever
// that has paid every time on this kernel.
// A swizzle: 16B-slot involution s ^= (s>>3)&7; LDS dest linear, global
// source pre-swizzled (rule 21), frag reads apply same involution.
// ---------------------------------------------------------------------------
__global__ __launch_bounds__(256, 4) void sims_kernel(
    const _Float16* __restrict__ Ah, const _Float16* __restrict__ Bh,
    const int* __restrict__ img_lens, const int* __restrict__ cap_lens,
    float* __restrict__ out) {
  __shared__ char stage[2 * ABUF] __attribute__((aligned(16)));

  int tid = threadIdx.x;
  int lane = tid & 63;
  int w = tid >> 6;       // wave = caption within quad

  // ---- XCD-aware remap (R7): 4 caption-quads per XCD, by shared x4 ----
  int wgid = blockIdx.x;
  int xcd = wgid & 7;
  int slot = wgid >> 3;            // 0..255
  int bx = 4 * xcd + (slot & 3);   // caption quad 0..31
  int by = slot >> 2;              // image pair 0..63

  int fr = lane & 15;
  int fq = lane >> 4;

  const size_t arow0 = (size_t)by * MB;

  // ---- A staging: 6 chunks of 1 KB; waves own {0-1},{2-3},{4},{5} ----
  const int c0 = (w < 2) ? 2 * w : w + 2;
  const int nch = (w < 2) ? 2 : 1;
  int s0 = c0 * 64 + lane;
  int sw0 = s0 ^ ((s0 >> 3) & 7);
  const _Float16* gpA = Ah + (arow0 + (sw0 >> 2)) * DD + (sw0 & 3) * 8;
  const int lds0 = c0 * 1024 + lane * 16;

  // ---- af LDS read base: swizzle XOR is mi-invariant (64mi ≡ 0 mod 8) ----
  int sl = 4 * fr + fq;
  const int aoff0 = (sl ^ ((sl >> 3) & 7)) * 16;

  // ---- B fragment-major pointers: frag(ni, t) at bp[ni] + 512*t halves ----
  const _Float16* bp[4];
#pragma unroll
  for (int ni = 0; ni < 4; ++ni)
    bp[ni] = Bh + ((size_t)((bx * 16) + 4 * w + ni) * 32) * 512 + lane * 8;

  f4 acc[6][4] = {};
  h8 bfA[4], bfB[4];

  auto STAGE = [&](int buf, int k0) {
    __builtin_amdgcn_global_load_lds(
        (const __attribute__((address_space(1))) void*)(gpA + k0),
        (__attribute__((address_space(3))) void*)(stage + buf * ABUF + lds0), 16, 0, 0);
    if (nch == 2)
      __builtin_amdgcn_global_load_lds(
          (const __attribute__((address_space(1))) void*)(gpA + 16 * DD + k0),
          (__attribute__((address_space(3))) void*)(stage + buf * ABUF + lds0 + 1024), 16, 0, 0);
  };
  auto LOADB = [&](h8(&bf)[4], int t) {
#pragma unroll
    for (int ni = 0; ni < 4; ++ni) bf[ni] = *(const h8*)(bp[ni] + 512 * t);
  };
  // one step: prefetch A(t+1)+B(t+1), compute(t), barrier (drains prefetch)
  auto BODY = [&](int t, int parity, h8(&cur)[4], h8(&nxt)[4]) {
    if (t < 31) {
      STAGE(parity ^ 1, 32 * (t + 1));   // buf(t+1): reads of it at t-1 done
      LOADB(nxt, t + 1);
    }
    const char* rb = stage + parity * ABUF;
    h8 af[6];
#pragma unroll
    for (int mi = 0; mi < 6; ++mi)
      af[mi] = *(const h8*)(rb + aoff0 + 1024 * mi);
    __builtin_amdgcn_s_setprio(1);
#pragma unroll
    for (int mi = 0; mi < 6; ++mi)
#pragma unroll
      for (int ni = 0; ni < 4; ++ni)
        acc[mi][ni] = __builtin_amdgcn_mfma_f32_16x16x32_f16(
            af[mi], cur[ni], acc[mi][ni], 0, 0, 0);
    __builtin_amdgcn_s_setprio(0);
    __syncthreads();   // vmcnt(0)+barrier: A(t+1)/B(t+1) had full compute to land
  };

  // ---- prologue: A(0)->buf0, B(0)->regs ----
  STAGE(0, 0);
  LOADB(bfA, 0);
  __syncthreads();

  for (int tt = 0; tt < 32; tt += 2) {
    BODY(tt, 0, bfA, bfB);
    BODY(tt + 1, 1, bfB, bfA);
  }

  // ---- register epilogue: C/D layout col=16*ni+fr, row=16*mi+4*fq+j ----
  int t = bx * 4 + w;
  int Lt = cap_lens[t];

#pragma unroll
  for (int img = 0; img < 2; ++img) {
    int Ki = img_lens[2 * by + img];

    float m = -1e30f;
#pragma unroll
    for (int mi = 0; mi < 3; ++mi)
#pragma unroll
      for (int ni = 0; ni < 4; ++ni)
#pragma unroll
        for (int j = 0; j < 4; ++j) {
          bool valid = (16 * mi + 4 * fq + j < Ki) && (16 * ni + fr < Lt);
          if (valid) m = fmaxf(m, acc[3 * img + mi][ni][j]);
        }
    m = wave_red_max(m);

    float rowe[3][4] = {}, rowes[3][4] = {}, cole[4] = {}, coles[4] = {};
#pragma unroll
    for (int mi = 0; mi < 3; ++mi)
#pragma unroll
      for (int ni = 0; ni < 4; ++ni)
#pragma unroll
        for (int j = 0; j < 4; ++j) {
          float s = acc[3 * img + mi][ni][j];
          bool valid = (16 * mi + 4 * fq + j < Ki) && (16 * ni + fr < Lt);
          float e = valid ? __expf((s - m) * 20.0f) : 0.f;  // 1/LAMB = 20
          float es = e * s;
          rowe[mi][j] += e;
          rowes[mi][j] += es;
          cole[ni] += e;
          coles[ni] += es;
        }

    // v2t: per row, reduce over cols (fr lanes), then accumulate rows
    float part = 0.f;
#pragma unroll
    for (int mi = 0; mi < 3; ++mi)
#pragma unroll
      for (int j = 0; j < 4; ++j) {
        float Re = rowe[mi][j], Res = rowes[mi][j];
#pragma unroll
        for (int o = 1; o < 16; o <<= 1) {
          Re += __shfl_xor(Re, o, 64);
          Res += __shfl_xor(Res, o, 64);
        }
        int row = 16 * mi + 4 * fq + j;
        if (fr == 0 && row < Ki) part += (Res / Re) * (0.5f / (float)Ki);
      }
    // t2v: per col, reduce over rows (fq lanes), then accumulate cols
#pragma unroll
    for (int ni = 0; ni < 4; ++ni) {
      float Ce = cole[ni], Ces = coles[ni];
#pragma unroll
      for (int o = 16; o < 64; o <<= 1) {
        Ce += __shfl_xor(Ce, o, 64);
        Ces += __shfl_xor(Ces, o, 64);
      }
      int l = 16 * ni + fr;
      if (fq == 0 && l < Lt) part += (Ces / Ce) * (0.5f / (float)Lt);
    }
    float sim = wave_red_sum(part);
    if (lane == 0) out[(size_t)(2 * by + img) * BT + t] = sim;
  }
}

extern "C" void kernel_launch(void* const* d_in, const int* in_sizes, int n_in,
                              void* d_out, int out_size, void* d_ws, size_t ws_size,
                              hipStream_t stream) {
  // setup_inputs order: img_cls, imgs, cap_cls, caps, img_lens, cap_lens
  const float* imgs = (const float*)d_in[1];
  const float* caps = (const float*)d_in[3];
  const int* img_lens = (const int*)d_in[4];
  const int* cap_lens = (const int*)d_in[5];
  float* out = (float*)d_out;

  _Float16* Ah = (_Float16*)d_ws;                    // [BI*MP][DD] = 12.6 MB
  _Float16* Bh = Ah + (size_t)BI * MP * DD;          // fragment-major, 16.8 MB

  norm_kernel<<<BI * MP + BT * LCAP, 256, 0, stream>>>(imgs, caps, Ah, Bh);
  sims_kernel<<<2048, 256, 0, stream>>>(Ah, Bh, img_lens, cap_lens, out);
}

// Round 13
// 477.321 us; speedup vs baseline: 1.4823x; 1.4823x over previous
//
#include <hip/hip_runtime.h>
#include <stdint.h>

#define BI 128
#define BT 128
#define KIMG 36
#define LCAP 64
#define DD 1024
#define MP 48        // imgs K padded to 3x16 for MFMA alignment
#define MB 96        // rows per block = 2 padded images
#define NB 256       // cols per block = 4 captions
#define ABUF 6144    // one A staging buffer: 96 rows x 64 B

typedef _Float16 h4 __attribute__((ext_vector_type(4)));
typedef _Float16 h8 __attribute__((ext_vector_type(8)));
typedef float f4 __attribute__((ext_vector_type(4)));

__device__ __forceinline__ float wave_red_sum(float v) {
#pragma unroll
  for (int o = 1; o < 64; o <<= 1) v += __shfl_xor(v, o, 64);
  return v;
}
__device__ __forceinline__ float wave_red_max(float v) {
#pragma unroll
  for (int o = 1; o < 64; o <<= 1) v = fmaxf(v, __shfl_xor(v, o, 64));
  return v;
}

// ---------------------------------------------------------------------------
// Kernel 1: add EPS, L2-normalize rows over D=1024, cast to fp16.
// imgs -> padded row-major [BI*MP][DD] (rows 36..47 of each image = 0).
// caps -> FRAGMENT-MAJOR Bh: tile (r/16, k/32) of 512 halves; within a tile
// half-offset = lane*8 where lane = (kk>>3)*16 + (r&15), kk = k&31. This makes
// a GEMM wave's bf[ni] fragment load one contiguous, coalesced 1 KB segment.
// ---------------------------------------------------------------------------
__global__ __launch_bounds__(256) void norm_kernel(
    const float* __restrict__ imgs, const float* __restrict__ caps,
    _Float16* __restrict__ Ah, _Float16* __restrict__ Bh) {
  int row = blockIdx.x;
  int tid = threadIdx.x;
  const float* src;
  bool isCap;
  int r = 0;
  if (row < BI * MP) {
    int i = row / MP, k = row - i * MP;
    isCap = false;
    if (k >= KIMG) {           // zero padding rows (block-uniform branch)
      h4 z = {};
      ((h4*)(Ah + (size_t)row * DD))[tid] = z;
      return;
    }
    src = imgs + ((size_t)i * KIMG + k) * DD;
  } else {
    r = row - BI * MP;
    isCap = true;
    src = caps + (size_t)r * DD;
  }
  float4 x = ((const float4*)src)[tid];
  x.x += 1e-6f; x.y += 1e-6f; x.z += 1e-6f; x.w += 1e-6f;
  float ss = x.x * x.x + x.y * x.y + x.z * x.z + x.w * x.w;
  ss = wave_red_sum(ss);
  __shared__ float red[4];
  int lane = tid & 63, w = tid >> 6;
  if (lane == 0) red[w] = ss;
  __syncthreads();
  float scale = rsqrtf(red[0] + red[1] + red[2] + red[3]);
  h4 o;
  o[0] = (_Float16)(x.x * scale);
  o[1] = (_Float16)(x.y * scale);
  o[2] = (_Float16)(x.z * scale);
  o[3] = (_Float16)(x.w * scale);
  if (!isCap) {
    ((h4*)(Ah + (size_t)row * DD))[tid] = o;
  } else {
    int k = 4 * tid;
    size_t tile = (size_t)(r >> 4) * 32 + (k >> 5);
    int sub = ((k >> 3) & 3) * 128 + (r & 15) * 8 + (k & 7);
    *(h4*)(Bh + tile * 512 + sub) = o;
  }
}

// ---------------------------------------------------------------------------
// Kernel 2: 2 images x 4 captions per block (96x256), wave w = caption w.
// R11 structure (B never touches LDS) + 2-DEEP B PREFETCH (T4 counted vmcnt):
//  - A (shared): swizzled LDS dbuf, 6 KB/step; A(t+1) staged during step t.
//  - B (wave-private): fragment-major coalesced 1KB loads, THREE reg sets,
//    B(t+2) issued during step t -> 2 full steps of flight time.
//  - End of step t: s_waitcnt vmcnt(4) retires A(t+1)+B(t+1), KEEPS B(t+2)
//    in flight across the raw s_barrier (in-order: newest 4 = B(t+2)).
// WAR on A dbuf: reads(t) retire via compiler lgkm-waits before MFMAs(t),
// which precede the end-of-t barrier; STAGE(t+2) into that buf is after it.
// A swizzle: 16B-slot involution s ^= (s>>3)&7; LDS dest linear, global
// source pre-swizzled (rule 21), frag reads apply same involution.
// ---------------------------------------------------------------------------
__global__ __launch_bounds__(256, 3) void sims_kernel(
    const _Float16* __restrict__ Ah, const _Float16* __restrict__ Bh,
    const int* __restrict__ img_lens, const int* __restrict__ cap_lens,
    float* __restrict__ out) {
  __shared__ char stage[2 * ABUF] __attribute__((aligned(16)));

  int tid = threadIdx.x;
  int lane = tid & 63;
  int w = tid >> 6;       // wave = caption within quad

  // ---- XCD-aware remap (R7): 4 caption-quads per XCD, by shared x4 ----
  int wgid = blockIdx.x;
  int xcd = wgid & 7;
  int slot = wgid >> 3;            // 0..255
  int bx = 4 * xcd + (slot & 3);   // caption quad 0..31
  int by = slot >> 2;              // image pair 0..63

  int fr = lane & 15;
  int fq = lane >> 4;

  const size_t arow0 = (size_t)by * MB;

  // ---- A staging: 6 chunks of 1 KB; waves own {0-1},{2-3},{4},{5} ----
  const int c0 = (w < 2) ? 2 * w : w + 2;
  const int nch = (w < 2) ? 2 : 1;
  int s0 = c0 * 64 + lane;
  int sw0 = s0 ^ ((s0 >> 3) & 7);
  const _Float16* gpA = Ah + (arow0 + (sw0 >> 2)) * DD + (sw0 & 3) * 8;
  const int lds0 = c0 * 1024 + lane * 16;

  // ---- af LDS read base: swizzle XOR is mi-invariant (64mi ≡ 0 mod 8) ----
  int sl = 4 * fr + fq;
  const int aoff0 = (sl ^ ((sl >> 3) & 7)) * 16;

  // ---- B fragment-major pointers: frag(ni, t) at bp[ni] + 512*t halves ----
  const _Float16* bp[4];
#pragma unroll
  for (int ni = 0; ni < 4; ++ni)
    bp[ni] = Bh + ((size_t)((bx * 16) + 4 * w + ni) * 32) * 512 + lane * 8;

  f4 acc[6][4] = {};
  h8 bfA[4], bfB[4], bfC[4];

  auto STAGE = [&](int buf, int k0) {
    __builtin_amdgcn_global_load_lds(
        (const __attribute__((address_space(1))) void*)(gpA + k0),
        (__attribute__((address_space(3))) void*)(stage + buf * ABUF + lds0), 16, 0, 0);
    if (nch == 2)
      __builtin_amdgcn_global_load_lds(
          (const __attribute__((address_space(1))) void*)(gpA + 16 * DD + k0),
          (__attribute__((address_space(3))) void*)(stage + buf * ABUF + lds0 + 1024), 16, 0, 0);
  };
  auto LOADB = [&](h8(&bf)[4], int t) {
#pragma unroll
    for (int ni = 0; ni < 4; ++ni) bf[ni] = *(const h8*)(bp[ni] + 512 * t);
  };
  auto COMPUTE = [&](int parity, h8(&cur)[4]) {
    const char* rb = stage + parity * ABUF;
    h8 af[6];
#pragma unroll
    for (int mi = 0; mi < 6; ++mi)
      af[mi] = *(const h8*)(rb + aoff0 + 1024 * mi);
    __builtin_amdgcn_s_setprio(1);
#pragma unroll
    for (int mi = 0; mi < 6; ++mi)
#pragma unroll
      for (int ni = 0; ni < 4; ++ni)
        acc[mi][ni] = __builtin_amdgcn_mfma_f32_16x16x32_f16(
            af[mi], cur[ni], acc[mi][ni], 0, 0, 0);
    __builtin_amdgcn_s_setprio(0);
  };
  // step t (t<=29): issue A(t+1), B(t+2); compute(t); retire A(t+1)+B(t+1),
  // keep B(t+2) (4 newest) in flight across the barrier.
  auto BODY = [&](int t, h8(&cur)[4], h8(&nxt2)[4]) {
    STAGE((t + 1) & 1, 32 * (t + 1));
    LOADB(nxt2, t + 2);
    COMPUTE(t & 1, cur);
    asm volatile("s_waitcnt vmcnt(4)" ::: "memory");
    __builtin_amdgcn_s_barrier();
    __builtin_amdgcn_sched_barrier(0);
  };

  // ---- prologue: A(0)->buf0, B(0), B(1); retire A(0)+B(0), keep B(1) ----
  STAGE(0, 0);
  LOADB(bfA, 0);
  LOADB(bfB, 1);
  asm volatile("s_waitcnt vmcnt(4)" ::: "memory");
  __builtin_amdgcn_s_barrier();
  __builtin_amdgcn_sched_barrier(0);

  // ---- main loop: t = 0..29, unroll 6 = lcm(A-parity 2, B-rotation 3) ----
  for (int tt = 0; tt < 30; tt += 6) {
    BODY(tt + 0, bfA, bfC);
    BODY(tt + 1, bfB, bfA);
    BODY(tt + 2, bfC, bfB);
    BODY(tt + 3, bfA, bfC);
    BODY(tt + 4, bfB, bfA);
    BODY(tt + 5, bfC, bfB);
  }
  // t = 30: issue A(31); compute B(30)=bfA; drain everything
  STAGE(1, 32 * 31);
  COMPUTE(0, bfA);
  asm volatile("s_waitcnt vmcnt(0)" ::: "memory");
  __builtin_amdgcn_s_barrier();
  __builtin_amdgcn_sched_barrier(0);
  // t = 31: compute B(31)=bfB
  COMPUTE(1, bfB);

  // ---- register epilogue: C/D layout col=16*ni+fr, row=16*mi+4*fq+j ----
  int t = bx * 4 + w;
  int Lt = cap_lens[t];

#pragma unroll
  for (int img = 0; img < 2; ++img) {
    int Ki = img_lens[2 * by + img];

    float m = -1e30f;
#pragma unroll
    for (int mi = 0; mi < 3; ++mi)
#pragma unroll
      for (int ni = 0; ni < 4; ++ni)
#pragma unroll
        for (int j = 0; j < 4; ++j) {
          bool valid = (16 * mi + 4 * fq + j < Ki) && (16 * ni + fr < Lt);
          if (valid) m = fmaxf(m, acc[3 * img + mi][ni][j]);
        }
    m = wave_red_max(m);

    float rowe[3][4] = {}, rowes[3][4] = {}, cole[4] = {}, coles[4] = {};
#pragma unroll
    for (int mi = 0; mi < 3; ++mi)
#pragma unroll
      for (int ni = 0; ni < 4; ++ni)
#pragma unroll
        for (int j = 0; j < 4; ++j) {
          float s = acc[3 * img + mi][ni][j];
          bool valid = (16 * mi + 4 * fq + j < Ki) && (16 * ni + fr < Lt);
          float e = valid ? __expf((s - m) * 20.0f) : 0.f;  // 1/LAMB = 20
          float es = e * s;
          rowe[mi][j] += e;
          rowes[mi][j] += es;
          cole[ni] += e;
          coles[ni] += es;
        }

    // v2t: per row, reduce over cols (fr lanes), then accumulate rows
    float part = 0.f;
#pragma unroll
    for (int mi = 0; mi < 3; ++mi)
#pragma unroll
      for (int j = 0; j < 4; ++j) {
        float Re = rowe[mi][j], Res = rowes[mi][j];
#pragma unroll
        for (int o = 1; o < 16; o <<= 1) {
          Re += __shfl_xor(Re, o, 64);
          Res += __shfl_xor(Res, o, 64);
        }
        int row = 16 * mi + 4 * fq + j;
        if (fr == 0 && row < Ki) part += (Res / Re) * (0.5f / (float)Ki);
      }
    // t2v: per col, reduce over rows (fq lanes), then accumulate cols
#pragma unroll
    for (int ni = 0; ni < 4; ++ni) {
      float Ce = cole[ni], Ces = coles[ni];
#pragma unroll
      for (int o = 16; o < 64; o <<= 1) {
        Ce += __shfl_xor(Ce, o, 64);
        Ces += __shfl_xor(Ces, o, 64);
      }
      int l = 16 * ni + fr;
      if (fq == 0 && l < Lt) part += (Ces / Ce) * (0.5f / (float)Lt);
    }
    float sim = wave_red_sum(part);
    if (lane == 0) out[(size_t)(2 * by + img) * BT + t] = sim;
  }
}

extern "C" void kernel_launch(void* const* d_in, const int* in_sizes, int n_in,
                              void* d_out, int out_size, void* d_ws, size_t ws_size,
                              hipStream_t stream) {
  // setup_inputs order: img_cls, imgs, cap_cls, caps, img_lens, cap_lens
  const float* imgs = (const float*)d_in[1];
  const float* caps = (const float*)d_in[3];
  const int* img_lens = (const int*)d_in[4];
  const int* cap_lens = (const int*)d_in[5];
  float* out = (float*)d_out;

  _Float16* Ah = (_Float16*)d_ws;                    // [BI*MP][DD] = 12.6 MB
  _Float16* Bh = Ah + (size_t)BI * MP * DD;          // fragment-major, 16.8 MB

  norm_kernel<<<BI * MP + BT * LCAP, 256, 0, stream>>>(imgs, caps, Ah, Bh);
  sims_kernel<<<2048, 256, 0, stream>>>(Ah, Bh, img_lens, cap_lens, out);
}

// Round 14
// 132.821 us; speedup vs baseline: 5.3270x; 3.5937x over previous
//
#include <hip/hip_runtime.h>
#include <stdint.h>

#define BI 128
#define BT 128
#define KIMG 36
#define LCAP 64
#define DD 1024
#define MP 48        // imgs K padded to 3x16 for MFMA alignment
#define MB 96        // rows per block = 2 padded images
#define NB 256       // cols per block = 4 captions
#define ABUF 6144    // one A staging buffer: 96 rows x 64 B

typedef _Float16 h4 __attribute__((ext_vector_type(4)));
typedef _Float16 h8 __attribute__((ext_vector_type(8)));
typedef float f4 __attribute__((ext_vector_type(4)));

__device__ __forceinline__ float wave_red_sum(float v) {
#pragma unroll
  for (int o = 1; o < 64; o <<= 1) v += __shfl_xor(v, o, 64);
  return v;
}
__device__ __forceinline__ float wave_red_max(float v) {
#pragma unroll
  for (int o = 1; o < 64; o <<= 1) v = fmaxf(v, __shfl_xor(v, o, 64));
  return v;
}

// ---------------------------------------------------------------------------
// Kernel 1: add EPS, L2-normalize rows over D=1024, cast to fp16.
// ONE WAVE PER ROW (4 rows / 256-thread block): pure shuffle reduction, no
// LDS, no __syncthreads. Each lane owns 4 float4 at stride-64.
// imgs -> padded row-major [BI*MP][DD] (rows 36..47 of each image = 0).
// caps -> FRAGMENT-MAJOR Bh: tile (r/16, k/32) of 512 halves; within a tile
// half-offset = lane*8 where lane = (kk>>3)*16 + (r&15), kk = k&31. This makes
// a GEMM wave's bf[ni] fragment load one contiguous, coalesced 1 KB segment.
// ---------------------------------------------------------------------------
__global__ __launch_bounds__(256) void norm_kernel(
    const float* __restrict__ imgs, const float* __restrict__ caps,
    _Float16* __restrict__ Ah, _Float16* __restrict__ Bh) {
  int lane = threadIdx.x & 63;
  int wv = threadIdx.x >> 6;
  int row = blockIdx.x * 4 + wv;          // 0 .. BI*MP + BT*LCAP - 1
  const float* src;
  bool isCap;
  int r = 0;
  if (row < BI * MP) {
    int i = row / MP, k = row - i * MP;
    isCap = false;
    if (k >= KIMG) {                      // zero padding rows (wave-uniform)
      h4 z = {};
#pragma unroll
      for (int seg = 0; seg < 4; ++seg)
        ((h4*)(Ah + (size_t)row * DD))[lane + 64 * seg] = z;
      return;
    }
    src = imgs + ((size_t)i * KIMG + k) * DD;
  } else {
    r = row - BI * MP;
    isCap = true;
    src = caps + (size_t)r * DD;
  }
  float4 x[4];
  float ss = 0.f;
#pragma unroll
  for (int seg = 0; seg < 4; ++seg) {
    x[seg] = ((const float4*)src)[lane + 64 * seg];
    x[seg].x += 1e-6f; x[seg].y += 1e-6f; x[seg].z += 1e-6f; x[seg].w += 1e-6f;
    ss += x[seg].x * x[seg].x + x[seg].y * x[seg].y +
          x[seg].z * x[seg].z + x[seg].w * x[seg].w;
  }
  ss = wave_red_sum(ss);
  float scale = rsqrtf(ss);
#pragma unroll
  for (int seg = 0; seg < 4; ++seg) {
    h4 o;
    o[0] = (_Float16)(x[seg].x * scale);
    o[1] = (_Float16)(x[seg].y * scale);
    o[2] = (_Float16)(x[seg].z * scale);
    o[3] = (_Float16)(x[seg].w * scale);
    if (!isCap) {
      ((h4*)(Ah + (size_t)row * DD))[lane + 64 * seg] = o;
    } else {
      int k = 4 * (lane + 64 * seg);
      size_t tile = (size_t)(r >> 4) * 32 + (k >> 5);
      int sub = ((k >> 3) & 3) * 128 + (r & 15) * 8 + (k & 7);
      *(h4*)(Bh + tile * 512 + sub) = o;
    }
  }
}

// ---------------------------------------------------------------------------
// Kernel 2 (byte-exact R11 champion): 2 images x 4 captions per block
// (96x256), wave w = caption w. B never touches LDS:
//  - A (shared by 4 waves): swizzled LDS dbuf, 6 KB/step (12.3 KB total).
//  - B (wave-private): fragment-major coalesced 1KB global->VGPR loads,
//    ping-pong prefetched one step ahead, drained by end-of-step barrier.
// A swizzle: 16B-slot involution s ^= (s>>3)&7; LDS dest linear, global
// source pre-swizzled (rule 21), frag reads apply same involution.
// ---------------------------------------------------------------------------
__global__ __launch_bounds__(256, 3) void sims_kernel(
    const _Float16* __restrict__ Ah, const _Float16* __restrict__ Bh,
    const int* __restrict__ img_lens, const int* __restrict__ cap_lens,
    float* __restrict__ out) {
  __shared__ char stage[2 * ABUF] __attribute__((aligned(16)));

  int tid = threadIdx.x;
  int lane = tid & 63;
  int w = tid >> 6;       // wave = caption within quad

  // ---- XCD-aware remap (R7): 4 caption-quads per XCD, by shared x4 ----
  int wgid = blockIdx.x;
  int xcd = wgid & 7;
  int slot = wgid >> 3;            // 0..255
  int bx = 4 * xcd + (slot & 3);   // caption quad 0..31
  int by = slot >> 2;              // image pair 0..63

  int fr = lane & 15;
  int fq = lane >> 4;

  const size_t arow0 = (size_t)by * MB;

  // ---- A staging: 6 chunks of 1 KB; waves own {0-1},{2-3},{4},{5} ----
  const int c0 = (w < 2) ? 2 * w : w + 2;
  const int nch = (w < 2) ? 2 : 1;
  int s0 = c0 * 64 + lane;
  int sw0 = s0 ^ ((s0 >> 3) & 7);
  const _Float16* gpA = Ah + (arow0 + (sw0 >> 2)) * DD + (sw0 & 3) * 8;
  const int lds0 = c0 * 1024 + lane * 16;

  // ---- af LDS read base: swizzle XOR is mi-invariant (64mi ≡ 0 mod 8) ----
  int sl = 4 * fr + fq;
  const int aoff0 = (sl ^ ((sl >> 3) & 7)) * 16;

  // ---- B fragment-major pointers: frag(ni, t) at bp[ni] + 512*t halves ----
  const _Float16* bp[4];
#pragma unroll
  for (int ni = 0; ni < 4; ++ni)
    bp[ni] = Bh + ((size_t)((bx * 16) + 4 * w + ni) * 32) * 512 + lane * 8;

  f4 acc[6][4] = {};
  h8 bfA[4], bfB[4];

  auto STAGE = [&](int buf, int k0) {
    __builtin_amdgcn_global_load_lds(
        (const __attribute__((address_space(1))) void*)(gpA + k0),
        (__attribute__((address_space(3))) void*)(stage + buf * ABUF + lds0), 16, 0, 0);
    if (nch == 2)
      __builtin_amdgcn_global_load_lds(
          (const __attribute__((address_space(1))) void*)(gpA + 16 * DD + k0),
          (__attribute__((address_space(3))) void*)(stage + buf * ABUF + lds0 + 1024), 16, 0, 0);
  };
  auto LOADB = [&](h8(&bf)[4], int t) {
#pragma unroll
    for (int ni = 0; ni < 4; ++ni) bf[ni] = *(const h8*)(bp[ni] + 512 * t);
  };
  // one step: prefetch A(t+1)+B(t+1), compute(t), barrier (drains prefetch)
  auto BODY = [&](int t, int parity, h8(&cur)[4], h8(&nxt)[4]) {
    if (t < 31) {
      STAGE(parity ^ 1, 32 * (t + 1));   // buf(t+1): reads of it at t-1 done
      LOADB(nxt, t + 1);
    }
    const char* rb = stage + parity * ABUF;
    h8 af[6];
#pragma unroll
    for (int mi = 0; mi < 6; ++mi)
      af[mi] = *(const h8*)(rb + aoff0 + 1024 * mi);
    __builtin_amdgcn_s_setprio(1);
#pragma unroll
    for (int mi = 0; mi < 6; ++mi)
#pragma unroll
      for (int ni = 0; ni < 4; ++ni)
        acc[mi][ni] = __builtin_amdgcn_mfma_f32_16x16x32_f16(
            af[mi], cur[ni], acc[mi][ni], 0, 0, 0);
    __builtin_amdgcn_s_setprio(0);
    __syncthreads();   // vmcnt(0)+barrier: A(t+1)/B(t+1) had full compute to land
  };

  // ---- prologue: A(0)->buf0, B(0)->regs ----
  STAGE(0, 0);
  LOADB(bfA, 0);
  __syncthreads();

  for (int tt = 0; tt < 32; tt += 2) {
    BODY(tt, 0, bfA, bfB);
    BODY(tt + 1, 1, bfB, bfA);
  }

  // ---- register epilogue: C/D layout col=16*ni+fr, row=16*mi+4*fq+j ----
  int t = bx * 4 + w;
  int Lt = cap_lens[t];

#pragma unroll
  for (int img = 0; img < 2; ++img) {
    int Ki = img_lens[2 * by + img];

    float m = -1e30f;
#pragma unroll
    for (int mi = 0; mi < 3; ++mi)
#pragma unroll
      for (int ni = 0; ni < 4; ++ni)
#pragma unroll
        for (int j = 0; j < 4; ++j) {
          bool valid = (16 * mi + 4 * fq + j < Ki) && (16 * ni + fr < Lt);
          if (valid) m = fmaxf(m, acc[3 * img + mi][ni][j]);
        }
    m = wave_red_max(m);

    float rowe[3][4] = {}, rowes[3][4] = {}, cole[4] = {}, coles[4] = {};
#pragma unroll
    for (int mi = 0; mi < 3; ++mi)
#pragma unroll
      for (int ni = 0; ni < 4; ++ni)
#pragma unroll
        for (int j = 0; j < 4; ++j) {
          float s = acc[3 * img + mi][ni][j];
          bool valid = (16 * mi + 4 * fq + j < Ki) && (16 * ni + fr < Lt);
          float e = valid ? __expf((s - m) * 20.0f) : 0.f;  // 1/LAMB = 20
          float es = e * s;
          rowe[mi][j] += e;
          rowes[mi][j] += es;
          cole[ni] += e;
          coles[ni] += es;
        }

    // v2t: per row, reduce over cols (fr lanes), then accumulate rows
    float part = 0.f;
#pragma unroll
    for (int mi = 0; mi < 3; ++mi)
#pragma unroll
      for (int j = 0; j < 4; ++j) {
        float Re = rowe[mi][j], Res = rowes[mi][j];
#pragma unroll
        for (int o = 1; o < 16; o <<= 1) {
          Re += __shfl_xor(Re, o, 64);
          Res += __shfl_xor(Res, o, 64);
        }
        int row = 16 * mi + 4 * fq + j;
        if (fr == 0 && row < Ki) part += (Res / Re) * (0.5f / (float)Ki);
      }
    // t2v: per col, reduce over rows (fq lanes), then accumulate cols
#pragma unroll
    for (int ni = 0; ni < 4; ++ni) {
      float Ce = cole[ni], Ces = coles[ni];
#pragma unroll
      for (int o = 16; o < 64; o <<= 1) {
        Ce += __shfl_xor(Ce, o, 64);
        Ces += __shfl_xor(Ces, o, 64);
      }
      int l = 16 * ni + fr;
      if (fq == 0 && l < Lt) part += (Ces / Ce) * (0.5f / (float)Lt);
    }
    float sim = wave_red_sum(part);
    if (lane == 0) out[(size_t)(2 * by + img) * BT + t] = sim;
  }
}

extern "C" void kernel_launch(void* const* d_in, const int* in_sizes, int n_in,
                              void* d_out, int out_size, void* d_ws, size_t ws_size,
                              hipStream_t stream) {
  // setup_inputs order: img_cls, imgs, cap_cls, caps, img_lens, cap_lens
  const float* imgs = (const float*)d_in[1];
  const float* caps = (const float*)d_in[3];
  const int* img_lens = (const int*)d_in[4];
  const int* cap_lens = (const int*)d_in[5];
  float* out = (float*)d_out;

  _Float16* Ah = (_Float16*)d_ws;                    // [BI*MP][DD] = 12.6 MB
  _Float16* Bh = Ah + (size_t)BI * MP * DD;          // fragment-major, 16.8 MB

  norm_kernel<<<(BI * MP + BT * LCAP) / 4, 256, 0, stream>>>(imgs, caps, Ah, Bh);
  sims_kernel<<<2048, 256, 0, stream>>>(Ah, Bh, img_lens, cap_lens, out);
}